// Round 11
// baseline (289.921 us; speedup 1.0000x reference)
//
#include <hip/hip_runtime.h>
#include <hip/hip_bf16.h>

// GraphSAGE 3-layer, MI355X. Aggregate AFTER projection (mean-agg commutes
// with matmul), so edge gathers happen in 512-dim, not 4096-dim.
// R11: GEMM tile 128x128 -> 64x128. R10 showed co-residency was GRID-limited
// (632 blocks / 256 CU = 2.5), not capacity-limited; the per-k-step vmcnt
// drain needs more co-resident blocks to hide. 64x128 -> 1264 blocks,
// ~5/CU (LDS 24KB dbuf, launch_bounds(256,5)). A-tile uses the verified
// 2-rows-per-128B-line XOR layout (R10, measured 0 conflicts).

#define N_NODES 10000
#define N_EDGES 80000
#define F_DIM   4096
#define H_DIM   512
#define C_DIM   6
#define MP      10112   // 158 * 64, M padded for GEMM tiling

typedef __attribute__((ext_vector_type(4))) float f32x4;
typedef __attribute__((ext_vector_type(8))) short bf16x8;

__device__ __forceinline__ unsigned short f2bf(float f) {
  unsigned int u = __float_as_uint(f);
  u += 0x7FFFu + ((u >> 16) & 1u);   // round-to-nearest-even
  return (unsigned short)(u >> 16);
}

__device__ __forceinline__ f32x4 unpack_bf4(uint2 u) {
  f32x4 r;
  r[0] = __uint_as_float(u.x << 16);
  r[1] = __uint_as_float(u.x & 0xFFFF0000u);
  r[2] = __uint_as_float(u.y << 16);
  r[3] = __uint_as_float(u.y & 0xFFFF0000u);
  return r;
}

__device__ __forceinline__ void gload16(const short* g, short* l) {
  __builtin_amdgcn_global_load_lds(
      (const __attribute__((address_space(1))) unsigned int*)g,
      (__attribute__((address_space(3))) unsigned int*)l, 16, 0, 0);
}

// ---------------- CSR build ----------------
__global__ void count_deg(const int* __restrict__ dst, int* __restrict__ deg, int e) {
  int i = blockIdx.x * 256 + threadIdx.x;
  if (i < e) atomicAdd(&deg[dst[i]], 1);
}

// Single-block shuffle scan: 1024 threads x CH=10 contiguous elems = 10240 >= N.
// Also zeroes cur[] (used by fill_csr afterwards).
__global__ __launch_bounds__(1024) void scan_deg(const int* __restrict__ deg,
                                                 int* __restrict__ off,
                                                 float* __restrict__ inv_deg,
                                                 int* __restrict__ cur, int n) {
  __shared__ int wtot[16];
  const int CH = 10;
  int t = threadIdx.x;
  int lane = t & 63, wid = t >> 6;
  int base = t * CH;
  int v[CH];
  int s = 0;
#pragma unroll
  for (int j = 0; j < CH; ++j) {
    int i = base + j;
    v[j] = (i < n) ? deg[i] : 0;
    s += v[j];
  }
  int incl = s;
#pragma unroll
  for (int o = 1; o < 64; o <<= 1) {
    int u = __shfl_up(incl, o, 64);
    if (lane >= o) incl += u;
  }
  if (lane == 63) wtot[wid] = incl;
  __syncthreads();
  if (wid == 0 && lane < 16) {
    int w = wtot[lane];
    int wi = w;
#pragma unroll
    for (int o = 1; o < 16; o <<= 1) {
      int u = __shfl_up(wi, o, 64);
      if (lane >= o) wi += u;
    }
    wtot[lane] = wi - w;   // exclusive wave offset
  }
  __syncthreads();
  int run = wtot[wid] + incl - s;  // exclusive prefix for this thread's chunk
#pragma unroll
  for (int j = 0; j < CH; ++j) {
    int i = base + j;
    if (i < n) {
      run += v[j];
      off[i + 1] = run;
      inv_deg[i] = 1.0f / fmaxf((float)v[j], 1.0f);
      cur[i] = 0;
    }
  }
  if (t == 0) off[0] = 0;
}

__global__ void fill_csr(const int* __restrict__ src, const int* __restrict__ dst,
                         const int* __restrict__ off, int* __restrict__ cur,
                         int* __restrict__ csr, int e) {
  int i = blockIdx.x * 256 + threadIdx.x;
  if (i < e) {
    int d = dst[i];
    int p = atomicAdd(&cur[d], 1);
    csr[off[d] + p] = src[i];
  }
}

// ---------------- dtype conversion ----------------
// f32 -> bf16, 8 elems/thread; zero-fills the padded tail (idx >= nvalid).
__global__ void cvt_bf16(const float* __restrict__ s, short* __restrict__ d,
                         long nvalid, long ntotal) {
  long idx = ((long)blockIdx.x * 256 + threadIdx.x) * 8;
  if (idx >= ntotal) return;
  unsigned short o[8];
  if (idx < nvalid) {
    f32x4 a = *(const f32x4*)&s[idx];
    f32x4 b = *(const f32x4*)&s[idx + 4];
    o[0] = f2bf(a[0]); o[1] = f2bf(a[1]); o[2] = f2bf(a[2]); o[3] = f2bf(a[3]);
    o[4] = f2bf(b[0]); o[5] = f2bf(b[1]); o[6] = f2bf(b[2]); o[7] = f2bf(b[3]);
  } else {
    for (int j = 0; j < 8; ++j) o[j] = 0;
  }
  *(bf16x8*)&d[idx] = *(bf16x8*)o;
}

// fused weight conversion: [W1l;W1r]->Wc1, [W2l;W2r]->Wc2
__global__ void cvt_weights(const float* __restrict__ w1l, const float* __restrict__ w1r,
                            short* __restrict__ d1,
                            const float* __restrict__ w2l, const float* __restrict__ w2r,
                            short* __restrict__ d2) {
  const long h1 = (long)H_DIM * F_DIM;   // 512*4096
  const long h2 = (long)H_DIM * H_DIM;   // 512*512
  long idx = ((long)blockIdx.x * 256 + threadIdx.x) * 8;
  const float* s;
  short* d;
  if (idx < 2 * h1) {
    s = (idx < h1) ? (w1l + idx) : (w1r + (idx - h1));
    d = d1 + idx;
  } else {
    long off = idx - 2 * h1;
    if (off >= 2 * h2) return;
    s = (off < h2) ? (w2l + off) : (w2r + (off - h2));
    d = d2 + off;
  }
  f32x4 a = *(const f32x4*)s;
  f32x4 b = *(const f32x4*)(s + 4);
  unsigned short o[8];
  o[0] = f2bf(a[0]); o[1] = f2bf(a[1]); o[2] = f2bf(a[2]); o[3] = f2bf(a[3]);
  o[4] = f2bf(b[0]); o[5] = f2bf(b[1]); o[6] = f2bf(b[2]); o[7] = f2bf(b[3]);
  *(bf16x8*)d = *(bf16x8*)o;
}

// ---------------- bf16 MFMA GEMM: C[M][Nt] = A[M][K] @ B[Nt][K]^T, C bf16 ----
// 64x128 tile, 4 waves (2x2, each 32x64 out), 16x16x32 MFMA, BK=32.
// Double-buffered LDS (2 x 12KB = 24KB) -> 5 blocks/CU. Grid = (M/64)*(Nt/128)
// = 1264 blocks (vs 632): co-residency ~5/CU hides the per-k-step vmcnt drain.
// LDS layout (64B rows): 2 rows per 128B line, slot s = u ^ (L&7),
// u = (row&1)*4 | kslot (R10 scheme, measured 0 conflicts). gload_lds dest
// linear; global source inverse-permuted (both-sides rule). XCD block swizzle.
__global__ __launch_bounds__(256, 5) void gemm_bt(
    const short* __restrict__ A, const short* __restrict__ B,
    short* __restrict__ C, int Nt, int K) {
  __shared__ short lds[2 * 6144];   // buf: A @0 (2048 shorts), B @2048 (4096 shorts)
  const int tiles_n = Nt >> 7;
  const int cpx = gridDim.x >> 3;                       // blocks per XCD
  const int swz = (blockIdx.x & 7) * cpx + (blockIdx.x >> 3);
  const int bm = swz / tiles_n;
  const int bn = swz % tiles_n;
  const int t = threadIdx.x;
  const int lane = t & 63;
  const int w = t >> 6;
  const int wr = w >> 1, wc = w & 1;
  const int lr = lane & 15, lk = lane >> 4;

  f32x4 acc[2][4] = {};

  // staging map: physical 16B chunk c (LDS offset 16c within its region,
  // linear as gload_lds requires). L = c>>3 (128B line), s = c&7 (slot),
  // u = s ^ (L&7) -> holds row 2L+(u>>2), col (u&3)*8 shorts.
  // A: 1 chunk/thread (c = t, 256 chunks = 64x32). B: 2 (c = t, t+256).
  const short* pA;
  const short* pB[2];
  {
    int c = t;
    int L = c >> 3, s = c & 7;
    int u = s ^ (L & 7);
    int row = 2 * L + (u >> 2), col = (u & 3) * 8;
    pA = A + (size_t)(bm * 64 + row) * K + col;
  }
#pragma unroll
  for (int j = 0; j < 2; ++j) {
    int c = t + j * 256;
    int L = c >> 3, s = c & 7;
    int u = s ^ (L & 7);
    int row = 2 * L + (u >> 2), col = (u & 3) * 8;
    pB[j] = B + (size_t)(bn * 128 + row) * K + col;
  }

  const int NT = K >> 5;

  // prologue: stage tile 0 into buffer 0
  gload16(pA, lds + t * 8);
#pragma unroll
  for (int j = 0; j < 2; ++j) gload16(pB[j], lds + 2048 + (t + j * 256) * 8);
  __syncthreads();

  int cur = 0;
  for (int kt = 0; kt < NT; ++kt) {
    short* bufA = lds + cur * 6144;
    short* bufB = bufA + 2048;
    // phase 1: issue next-tile staging into the other buffer
    if (kt + 1 < NT) {
      int k0 = (kt + 1) << 5;
      short* nx = lds + (cur ^ 1) * 6144;
      gload16(pA + k0, nx + t * 8);
#pragma unroll
      for (int j = 0; j < 2; ++j) gload16(pB[j] + k0, nx + 2048 + (t + j * 256) * 8);
    }
    // phase 2: ds_read fragments (swizzled) + MFMA
    bf16x8 a[2], b[4];
#pragma unroll
    for (int m = 0; m < 2; ++m) {
      int r = wr * 32 + m * 16 + lr;
      int byte = (r >> 1) * 128 + ((((r & 1) * 4 + lk) ^ ((r >> 1) & 7)) * 16);
      a[m] = *(bf16x8*)((char*)bufA + byte);
    }
#pragma unroll
    for (int n = 0; n < 4; ++n) {
      int r = wc * 64 + n * 16 + lr;
      int byte = (r >> 1) * 128 + ((((r & 1) * 4 + lk) ^ ((r >> 1) & 7)) * 16);
      b[n] = *(bf16x8*)((char*)bufB + byte);
    }
#pragma unroll
    for (int m = 0; m < 2; ++m)
#pragma unroll
      for (int n = 0; n < 4; ++n)
        acc[m][n] = __builtin_amdgcn_mfma_f32_16x16x32_bf16(a[m], b[n], acc[m][n], 0, 0, 0);
    __syncthreads();   // drains next-tile gload_lds + LDS fence
    cur ^= 1;
  }

  const int crow0 = bm * 64 + wr * 32 + lk * 4;    // C/D: col=lane&15, row=(lane>>4)*4+j
  const int ccol0 = bn * 128 + wc * 64 + lr;
#pragma unroll
  for (int m = 0; m < 2; ++m)
#pragma unroll
    for (int n = 0; n < 4; ++n)
#pragma unroll
      for (int j = 0; j < 4; ++j)
        C[(size_t)(crow0 + m * 16 + j) * Nt + ccol0 + n * 16] =
            (short)f2bf(acc[m][n][j]);
}

// ---------------- fused CSR mean-aggregate + combine (bf16 Y, f32 accum) ----
// out_i = relu( mean_j Y[j][0:512] + b + Y[i][512:1024] ), write bf16 and/or f32.
__global__ __launch_bounds__(128) void agg_combine(
    const short* __restrict__ Y, const int* __restrict__ off, const int* __restrict__ csr,
    const float* __restrict__ inv_deg, const float* __restrict__ bias,
    short* __restrict__ hb, float* __restrict__ hf) {
  int i = blockIdx.x;
  int t = threadIdx.x;             // 4 bf16 cols (8B) of the 512 agg cols
  int e0 = off[i], e1 = off[i + 1];
  f32x4 s = {0.f, 0.f, 0.f, 0.f};
  for (int e = e0; e < e1; ++e) {
    int sn = csr[e];
    uint2 u = ((const uint2*)(Y + (size_t)sn * 1024))[t];   // row stride 1024 bf16
    s += unpack_bf4(u);
  }
  float id = inv_deg[i];
  uint2 zu = ((const uint2*)(Y + (size_t)i * 1024 + 512))[t];  // cols 512..1023
  f32x4 z = unpack_bf4(zu);
  f32x4 b = ((const f32x4*)bias)[t];
  f32x4 r;
#pragma unroll
  for (int j = 0; j < 4; ++j) r[j] = fmaxf(s[j] * id + b[j] + z[j], 0.f);
  if (hf) ((f32x4*)hf)[(size_t)i * 128 + t] = r;
  if (hb) {
    unsigned short o[4] = {f2bf(r[0]), f2bf(r[1]), f2bf(r[2]), f2bf(r[3])};
    *(uint2*)&hb[(size_t)i * 512 + t * 4] = *(uint2*)o;
  }
}

// ---------------- layer 3: [N,512] f32 @ [12,512]^T -> y3z3 [N][12] ----------------
// 16 rows per block (625 blocks, weight LDS-load amortized 4x).
__global__ __launch_bounds__(256) void l3_gemm(const float* __restrict__ h2,
                                               const float* __restrict__ w3l,
                                               const float* __restrict__ w3r,
                                               float* __restrict__ y3z3, int n) {
  __shared__ float wsh[12 * 512];
  int t = threadIdx.x;
  for (int idx = t; idx < 12 * 512; idx += 256) {
    int r = idx >> 9, c = idx & 511;
    wsh[idx] = (r < 6) ? w3l[r * 512 + c] : w3r[(r - 6) * 512 + c];
  }
  __syncthreads();
  int wid = t >> 6, lane = t & 63;
#pragma unroll
  for (int rr = 0; rr < 4; ++rr) {
    int row = blockIdx.x * 16 + rr * 4 + wid;
    if (row >= n) continue;
    const f32x4* h4 = (const f32x4*)(h2 + (size_t)row * 512);
    f32x4 ha = h4[lane * 2], hb = h4[lane * 2 + 1];
#pragma unroll
    for (int c = 0; c < 12; ++c) {
      const f32x4* w4 = (const f32x4*)&wsh[c * 512];
      f32x4 wa = w4[lane * 2], wb = w4[lane * 2 + 1];
      float s = ha[0] * wa[0] + ha[1] * wa[1] + ha[2] * wa[2] + ha[3] * wa[3]
              + hb[0] * wb[0] + hb[1] * wb[1] + hb[2] * wb[2] + hb[3] * wb[3];
#pragma unroll
      for (int o = 32; o; o >>= 1) s += __shfl_down(s, o, 64);
      if (lane == 0) y3z3[(size_t)row * 12 + c] = s;
    }
  }
}

__global__ void final_out(const float* __restrict__ y3z3, const int* __restrict__ off,
                          const int* __restrict__ csr, const float* __restrict__ inv_deg,
                          const float* __restrict__ b3, float* __restrict__ out, int n) {
  int idx = blockIdx.x * 256 + threadIdx.x;
  if (idx >= n * 6) return;
  int i = idx / 6, c = idx - i * 6;
  float s = 0.f;
  int e0 = off[i], e1 = off[i + 1];
  for (int e = e0; e < e1; ++e) s += y3z3[(size_t)csr[e] * 12 + c];
  out[idx] = s * inv_deg[i] + b3[c] + y3z3[(size_t)i * 12 + 6 + c];
}

// ---------------- host ----------------
extern "C" void kernel_launch(void* const* d_in, const int* in_sizes, int n_in,
                              void* d_out, int out_size, void* d_ws, size_t ws_size,
                              hipStream_t stream) {
  const float* x   = (const float*)d_in[0];
  const int*   ei  = (const int*)d_in[1];
  const float* W1l = (const float*)d_in[2];
  const float* b1  = (const float*)d_in[3];
  const float* W1r = (const float*)d_in[4];
  const float* W2l = (const float*)d_in[5];
  const float* b2  = (const float*)d_in[6];
  const float* W2r = (const float*)d_in[7];
  const float* W3l = (const float*)d_in[8];
  const float* b3  = (const float*)d_in[9];
  const float* W3r = (const float*)d_in[10];
  const int* src = ei;
  const int* dst = ei + N_EDGES;

  char* p = (char*)d_ws;
  auto alloc = [&](size_t bytes) { char* r = p; p += (bytes + 255) & ~(size_t)255; return r; };
  int*   deg     = (int*)alloc((size_t)N_NODES * 4);
  int*   off     = (int*)alloc((size_t)(N_NODES + 1) * 4);
  int*   cur     = (int*)alloc((size_t)N_NODES * 4);
  int*   csr     = (int*)alloc((size_t)N_EDGES * 4);
  float* inv_deg = (float*)alloc((size_t)N_NODES * 4);
  short* xb      = (short*)alloc((size_t)MP * F_DIM * 2);
  short* Wc1     = (short*)alloc((size_t)1024 * F_DIM * 2);
  short* Wc2     = (short*)alloc((size_t)1024 * H_DIM * 2);
  short* Cbuf    = (short*)alloc((size_t)MP * 1024 * 2);   // bf16 y|z
  short* hbuf    = (short*)alloc((size_t)MP * 512 * 2);
  float* y3z3    = (float*)alloc((size_t)N_NODES * 12 * 4);

  float* h_out   = (float*)d_out;                          // [N][512]
  float* o_out   = (float*)d_out + (size_t)N_NODES * 512;  // [N][6]

  // CSR build
  hipMemsetAsync(deg, 0, (size_t)N_NODES * 4, stream);
  count_deg<<<(N_EDGES + 255) / 256, 256, 0, stream>>>(dst, deg, N_EDGES);
  scan_deg<<<1, 1024, 0, stream>>>(deg, off, inv_deg, cur, N_NODES);
  fill_csr<<<(N_EDGES + 255) / 256, 256, 0, stream>>>(src, dst, off, cur, csr, N_EDGES);

  // x -> bf16 (padded rows zeroed); weights -> bf16 (both layers, one launch)
  {
    long ntotal = (long)MP * F_DIM;
    cvt_bf16<<<(int)((ntotal / 8 + 255) / 256), 256, 0, stream>>>(
        x, xb, (long)N_NODES * F_DIM, ntotal);
    long total = 2L * H_DIM * F_DIM + 2L * H_DIM * H_DIM;
    cvt_weights<<<(int)((total / 8 + 255) / 256), 256, 0, stream>>>(
        W1l, W1r, Wc1, W2l, W2r, Wc2);
  }

  // ---- layer 1 ----
  gemm_bt<<<(MP / 64) * (1024 / 128), 256, 0, stream>>>(xb, Wc1, Cbuf, 1024, F_DIM);
  agg_combine<<<N_NODES, 128, 0, stream>>>(Cbuf, off, csr, inv_deg, b1, hbuf, nullptr);

  // ---- layer 2 ----
  gemm_bt<<<(MP / 64) * (1024 / 128), 256, 0, stream>>>(hbuf, Wc2, Cbuf, 1024, H_DIM);
  agg_combine<<<N_NODES, 128, 0, stream>>>(Cbuf, off, csr, inv_deg, b2, nullptr, h_out);

  // ---- layer 3 ----
  l3_gemm<<<(N_NODES + 15) / 16, 256, 0, stream>>>(h_out, W3l, W3r, y3z3, N_NODES);
  final_out<<<(N_NODES * 6 + 255) / 256, 256, 0, stream>>>(y3z3, off, csr, inv_deg, b3, o_out, N_NODES);
}

// Round 12
// 261.076 us; speedup vs baseline: 1.1105x; 1.1105x over previous
//
#include <hip/hip_runtime.h>
#include <hip/hip_bf16.h>

// GraphSAGE 3-layer, MI355X. Aggregate AFTER projection (mean-agg commutes
// with matmul), so edge gathers happen in 512-dim, not 4096-dim.
// R12: kill the 40us cvt_bf16 pass by fusing it into gemm1 on the CONSUME
// side: A staged as RAW F32 into LDS via global_load_lds (no register
// liveness across phases -> immune to the R6-R9 sinking failure); the
// f32->bf16 conversion happens LDS->reg in the fragment read (ds_read_b128
// x2 + v_cvt_pk_bf16_f32 x4 per frag, short in-phase dependent chain).
// GEMM structure otherwise = R10 (measured best: 128x128, BK=32, dbuf).
// Layer-2 GEMM keeps the pure-bf16 R10 path (hbuf is already bf16).

#define N_NODES 10000
#define N_EDGES 80000
#define F_DIM   4096
#define H_DIM   512
#define C_DIM   6
#define MP      10112   // 79 * 128, M padded for GEMM tiling

typedef __attribute__((ext_vector_type(4))) float f32x4;
typedef __attribute__((ext_vector_type(8))) short bf16x8;

__device__ __forceinline__ unsigned short f2bf(float f) {
  unsigned int u = __float_as_uint(f);
  u += 0x7FFFu + ((u >> 16) & 1u);   // round-to-nearest-even
  return (unsigned short)(u >> 16);
}

__device__ __forceinline__ unsigned cvtpk(float a, float b) {
  unsigned r;   // r = bf16(a) | bf16(b)<<16  (RNE), memory order [a,b]
  asm("v_cvt_pk_bf16_f32 %0, %1, %2" : "=v"(r) : "v"(a), "v"(b));
  return r;
}

__device__ __forceinline__ f32x4 unpack_bf4(uint2 u) {
  f32x4 r;
  r[0] = __uint_as_float(u.x << 16);
  r[1] = __uint_as_float(u.x & 0xFFFF0000u);
  r[2] = __uint_as_float(u.y << 16);
  r[3] = __uint_as_float(u.y & 0xFFFF0000u);
  return r;
}

__device__ __forceinline__ void gload16(const void* g, short* l) {
  __builtin_amdgcn_global_load_lds(
      (const __attribute__((address_space(1))) unsigned int*)g,
      (__attribute__((address_space(3))) unsigned int*)l, 16, 0, 0);
}

// ---------------- CSR build ----------------
__global__ void count_deg(const int* __restrict__ dst, int* __restrict__ deg, int e) {
  int i = blockIdx.x * 256 + threadIdx.x;
  if (i < e) atomicAdd(&deg[dst[i]], 1);
}

// Single-block shuffle scan: 1024 threads x CH=10 contiguous elems = 10240 >= N.
// Also zeroes cur[] (used by fill_csr afterwards).
__global__ __launch_bounds__(1024) void scan_deg(const int* __restrict__ deg,
                                                 int* __restrict__ off,
                                                 float* __restrict__ inv_deg,
                                                 int* __restrict__ cur, int n) {
  __shared__ int wtot[16];
  const int CH = 10;
  int t = threadIdx.x;
  int lane = t & 63, wid = t >> 6;
  int base = t * CH;
  int v[CH];
  int s = 0;
#pragma unroll
  for (int j = 0; j < CH; ++j) {
    int i = base + j;
    v[j] = (i < n) ? deg[i] : 0;
    s += v[j];
  }
  int incl = s;
#pragma unroll
  for (int o = 1; o < 64; o <<= 1) {
    int u = __shfl_up(incl, o, 64);
    if (lane >= o) incl += u;
  }
  if (lane == 63) wtot[wid] = incl;
  __syncthreads();
  if (wid == 0 && lane < 16) {
    int w = wtot[lane];
    int wi = w;
#pragma unroll
    for (int o = 1; o < 16; o <<= 1) {
      int u = __shfl_up(wi, o, 64);
      if (lane >= o) wi += u;
    }
    wtot[lane] = wi - w;   // exclusive wave offset
  }
  __syncthreads();
  int run = wtot[wid] + incl - s;  // exclusive prefix for this thread's chunk
#pragma unroll
  for (int j = 0; j < CH; ++j) {
    int i = base + j;
    if (i < n) {
      run += v[j];
      off[i + 1] = run;
      inv_deg[i] = 1.0f / fmaxf((float)v[j], 1.0f);
      cur[i] = 0;
    }
  }
  if (t == 0) off[0] = 0;
}

__global__ void fill_csr(const int* __restrict__ src, const int* __restrict__ dst,
                         const int* __restrict__ off, int* __restrict__ cur,
                         int* __restrict__ csr, int e) {
  int i = blockIdx.x * 256 + threadIdx.x;
  if (i < e) {
    int d = dst[i];
    int p = atomicAdd(&cur[d], 1);
    csr[off[d] + p] = src[i];
  }
}

// fused weight conversion: [W1l;W1r]->Wc1, [W2l;W2r]->Wc2
__global__ void cvt_weights(const float* __restrict__ w1l, const float* __restrict__ w1r,
                            short* __restrict__ d1,
                            const float* __restrict__ w2l, const float* __restrict__ w2r,
                            short* __restrict__ d2) {
  const long h1 = (long)H_DIM * F_DIM;   // 512*4096
  const long h2 = (long)H_DIM * H_DIM;   // 512*512
  long idx = ((long)blockIdx.x * 256 + threadIdx.x) * 8;
  const float* s;
  short* d;
  if (idx < 2 * h1) {
    s = (idx < h1) ? (w1l + idx) : (w1r + (idx - h1));
    d = d1 + idx;
  } else {
    long off = idx - 2 * h1;
    if (off >= 2 * h2) return;
    s = (off < h2) ? (w2l + off) : (w2r + (off - h2));
    d = d2 + off;
  }
  f32x4 a = *(const f32x4*)s;
  f32x4 b = *(const f32x4*)(s + 4);
  unsigned short o[8];
  o[0] = f2bf(a[0]); o[1] = f2bf(a[1]); o[2] = f2bf(a[2]); o[3] = f2bf(a[3]);
  o[4] = f2bf(b[0]); o[5] = f2bf(b[1]); o[6] = f2bf(b[2]); o[7] = f2bf(b[3]);
  *(bf16x8*)d = *(bf16x8*)o;
}

// ---------------- bf16 MFMA GEMM: C[M][Nt] = A[M][K] @ B[Nt][K]^T, C bf16 ----
// 128x128 tile, 4 waves (2x2 of 64x64), 16x16x32 MFMA, BK=32, dbuf LDS,
// XCD block swizzle (R10 structure, measured best).
// AF32=1 (layer 1): A staged as F32 into LDS (16KB/buf) via gload_lds;
//   fragment read = 2x ds_read_b128 f32 + 4x v_cvt_pk_bf16_f32 (in-phase
//   chain, no cross-phase register liveness). Row layout: 32 f32 = 128B/row;
//   16B slot s holds kslot s^(row&7) -> per ds_read, 8 lanes per 4-bank slot
//   = 2/bank = free. Source rows >= Mvalid clamped (per-lane source is ok).
//   LDS 48KB -> 3 blocks/CU.
// AF32=0 (layer 2): pure bf16, R10 scheme (2 rows/128B line, XOR slots),
//   32KB -> 4 blocks/CU.
template<int AF32>
__global__ __launch_bounds__(256, AF32 ? 3 : 4) void gemm_bt_t(
    const void* __restrict__ Av, const short* __restrict__ B,
    short* __restrict__ C, int Mvalid, int Nt, int K) {
  __shared__ short lds[AF32 ? 2 * 12288 : 2 * 8192];
  const int BUFS = AF32 ? 12288 : 8192;   // shorts per buffer
  const int BOFF = AF32 ? 8192 : 4096;    // B region offset (shorts)
  const int tiles_n = Nt >> 7;
  const int cpx = gridDim.x >> 3;                       // blocks per XCD
  const int swz = (blockIdx.x & 7) * cpx + (blockIdx.x >> 3);
  const int bm = swz / tiles_n;
  const int bn = swz % tiles_n;
  const int t = threadIdx.x;
  const int lane = t & 63;
  const int w = t >> 6;
  const int wr = w >> 1, wc = w & 1;
  const int lr = lane & 15, lk = lane >> 4;

  f32x4 acc[4][4] = {};

  // ---- staging maps (gload_lds dest linear: chunk c -> LDS bytes 16c) ----
  // A, AF32: 1024 chunks (128 rows x 8 slots of 4 f32). c: row=c>>3, s=c&7,
  //   logical kslot = s ^ (row&7); src = x + grow*K + kslot*4 (f32).
  // A, bf16: 512 chunks, R10: L=c>>3, s=c&7, u=s^(L&7), row=2L+(u>>2),
  //   col=(u&3)*8 (shorts).
  // B: same R10 scheme, 512 chunks.
  const float* pAf[4];
  const short* pAh[2];
  const short* pB[2];
  if (AF32) {
    const float* xf = (const float*)Av;
#pragma unroll
    for (int j = 0; j < 4; ++j) {
      int c = t + j * 256;
      int row = c >> 3, s = c & 7;
      int kslot = s ^ (row & 7);
      int grow = bm * 128 + row;
      if (grow >= Mvalid) grow = Mvalid - 1;   // clamp: pad rows unread downstream
      pAf[j] = xf + (size_t)grow * K + kslot * 4;
    }
  } else {
    const short* Ah = (const short*)Av;
#pragma unroll
    for (int j = 0; j < 2; ++j) {
      int c = t + j * 256;
      int L = c >> 3, s = c & 7;
      int u = s ^ (L & 7);
      int row = 2 * L + (u >> 2), col = (u & 3) * 8;
      pAh[j] = Ah + (size_t)(bm * 128 + row) * K + col;
    }
  }
#pragma unroll
  for (int j = 0; j < 2; ++j) {
    int c = t + j * 256;
    int L = c >> 3, s = c & 7;
    int u = s ^ (L & 7);
    int row = 2 * L + (u >> 2), col = (u & 3) * 8;
    pB[j] = B + (size_t)(bn * 128 + row) * K + col;
  }

  const int NT = K >> 5;

  auto stage = [&](short* buf, int k0) {
    if (AF32) {
#pragma unroll
      for (int j = 0; j < 4; ++j) gload16(pAf[j] + k0, buf + (t + j * 256) * 8);
    } else {
#pragma unroll
      for (int j = 0; j < 2; ++j) gload16(pAh[j] + k0, buf + (t + j * 256) * 8);
    }
#pragma unroll
    for (int j = 0; j < 2; ++j) gload16(pB[j] + k0, buf + BOFF + (t + j * 256) * 8);
  };

  // prologue: stage tile 0 into buffer 0
  stage(lds, 0);
  __syncthreads();

  int cur = 0;
  for (int kt = 0; kt < NT; ++kt) {
    short* bufA = lds + cur * BUFS;
    short* bufB = bufA + BOFF;
    // phase 1: issue next-tile staging into the other buffer
    if (kt + 1 < NT) stage(lds + (cur ^ 1) * BUFS, (kt + 1) << 5);
    // phase 2: read fragments + MFMA
    bf16x8 a[4], b[4];
#pragma unroll
    for (int m = 0; m < 4; ++m) {
      int r = wr * 64 + m * 16 + lr;
      if (AF32) {
        // two f32x4 slots (kslot 2lk, 2lk+1), XOR-swizzled; cvt to bf16x8
        int byte0 = r * 128 + (((2 * lk + 0) ^ (r & 7)) * 16);
        int byte1 = r * 128 + (((2 * lk + 1) ^ (r & 7)) * 16);
        f32x4 q0 = *(const f32x4*)((const char*)bufA + byte0);
        f32x4 q1 = *(const f32x4*)((const char*)bufA + byte1);
        uint4 pk;
        pk.x = cvtpk(q0[0], q0[1]);
        pk.y = cvtpk(q0[2], q0[3]);
        pk.z = cvtpk(q1[0], q1[1]);
        pk.w = cvtpk(q1[2], q1[3]);
        a[m] = *(bf16x8*)&pk;
      } else {
        int byte = (r >> 1) * 128 + ((((r & 1) * 4 + lk) ^ ((r >> 1) & 7)) * 16);
        a[m] = *(bf16x8*)((char*)bufA + byte);
      }
    }
#pragma unroll
    for (int n = 0; n < 4; ++n) {
      int r = wc * 64 + n * 16 + lr;
      int byte = (r >> 1) * 128 + ((((r & 1) * 4 + lk) ^ ((r >> 1) & 7)) * 16);
      b[n] = *(bf16x8*)((char*)bufB + byte);
    }
#pragma unroll
    for (int m = 0; m < 4; ++m)
#pragma unroll
      for (int n = 0; n < 4; ++n)
        acc[m][n] = __builtin_amdgcn_mfma_f32_16x16x32_bf16(a[m], b[n], acc[m][n], 0, 0, 0);
    __syncthreads();   // drains next-tile gload_lds + LDS fence
    cur ^= 1;
  }

  const int crow0 = bm * 128 + wr * 64 + lk * 4;   // C/D: col=lane&15, row=(lane>>4)*4+j
  const int ccol0 = bn * 128 + wc * 64 + lr;
#pragma unroll
  for (int m = 0; m < 4; ++m)
#pragma unroll
    for (int n = 0; n < 4; ++n)
#pragma unroll
      for (int j = 0; j < 4; ++j)
        C[(size_t)(crow0 + m * 16 + j) * Nt + ccol0 + n * 16] =
            (short)f2bf(acc[m][n][j]);
}

// ---------------- fused CSR mean-aggregate + combine (bf16 Y, f32 accum) ----
// out_i = relu( mean_j Y[j][0:512] + b + Y[i][512:1024] ), write bf16 and/or f32.
__global__ __launch_bounds__(128) void agg_combine(
    const short* __restrict__ Y, const int* __restrict__ off, const int* __restrict__ csr,
    const float* __restrict__ inv_deg, const float* __restrict__ bias,
    short* __restrict__ hb, float* __restrict__ hf) {
  int i = blockIdx.x;
  int t = threadIdx.x;             // 4 bf16 cols (8B) of the 512 agg cols
  int e0 = off[i], e1 = off[i + 1];
  f32x4 s = {0.f, 0.f, 0.f, 0.f};
  for (int e = e0; e < e1; ++e) {
    int sn = csr[e];
    uint2 u = ((const uint2*)(Y + (size_t)sn * 1024))[t];   // row stride 1024 bf16
    s += unpack_bf4(u);
  }
  float id = inv_deg[i];
  uint2 zu = ((const uint2*)(Y + (size_t)i * 1024 + 512))[t];  // cols 512..1023
  f32x4 z = unpack_bf4(zu);
  f32x4 b = ((const f32x4*)bias)[t];
  f32x4 r;
#pragma unroll
  for (int j = 0; j < 4; ++j) r[j] = fmaxf(s[j] * id + b[j] + z[j], 0.f);
  if (hf) ((f32x4*)hf)[(size_t)i * 128 + t] = r;
  if (hb) {
    unsigned short o[4] = {f2bf(r[0]), f2bf(r[1]), f2bf(r[2]), f2bf(r[3])};
    *(uint2*)&hb[(size_t)i * 512 + t * 4] = *(uint2*)o;
  }
}

// ---------------- layer 3: [N,512] f32 @ [12,512]^T -> y3z3 [N][12] ----------------
// 16 rows per block (625 blocks, weight LDS-load amortized 4x).
__global__ __launch_bounds__(256) void l3_gemm(const float* __restrict__ h2,
                                               const float* __restrict__ w3l,
                                               const float* __restrict__ w3r,
                                               float* __restrict__ y3z3, int n) {
  __shared__ float wsh[12 * 512];
  int t = threadIdx.x;
  for (int idx = t; idx < 12 * 512; idx += 256) {
    int r = idx >> 9, c = idx & 511;
    wsh[idx] = (r < 6) ? w3l[r * 512 + c] : w3r[(r - 6) * 512 + c];
  }
  __syncthreads();
  int wid = t >> 6, lane = t & 63;
#pragma unroll
  for (int rr = 0; rr < 4; ++rr) {
    int row = blockIdx.x * 16 + rr * 4 + wid;
    if (row >= n) continue;
    const f32x4* h4 = (const f32x4*)(h2 + (size_t)row * 512);
    f32x4 ha = h4[lane * 2], hb = h4[lane * 2 + 1];
#pragma unroll
    for (int c = 0; c < 12; ++c) {
      const f32x4* w4 = (const f32x4*)&wsh[c * 512];
      f32x4 wa = w4[lane * 2], wb = w4[lane * 2 + 1];
      float s = ha[0] * wa[0] + ha[1] * wa[1] + ha[2] * wa[2] + ha[3] * wa[3]
              + hb[0] * wb[0] + hb[1] * wb[1] + hb[2] * wb[2] + hb[3] * wb[3];
#pragma unroll
      for (int o = 32; o; o >>= 1) s += __shfl_down(s, o, 64);
      if (lane == 0) y3z3[(size_t)row * 12 + c] = s;
    }
  }
}

__global__ void final_out(const float* __restrict__ y3z3, const int* __restrict__ off,
                          const int* __restrict__ csr, const float* __restrict__ inv_deg,
                          const float* __restrict__ b3, float* __restrict__ out, int n) {
  int idx = blockIdx.x * 256 + threadIdx.x;
  if (idx >= n * 6) return;
  int i = idx / 6, c = idx - i * 6;
  float s = 0.f;
  int e0 = off[i], e1 = off[i + 1];
  for (int e = e0; e < e1; ++e) s += y3z3[(size_t)csr[e] * 12 + c];
  out[idx] = s * inv_deg[i] + b3[c] + y3z3[(size_t)i * 12 + 6 + c];
}

// ---------------- host ----------------
extern "C" void kernel_launch(void* const* d_in, const int* in_sizes, int n_in,
                              void* d_out, int out_size, void* d_ws, size_t ws_size,
                              hipStream_t stream) {
  const float* x   = (const float*)d_in[0];
  const int*   ei  = (const int*)d_in[1];
  const float* W1l = (const float*)d_in[2];
  const float* b1  = (const float*)d_in[3];
  const float* W1r = (const float*)d_in[4];
  const float* W2l = (const float*)d_in[5];
  const float* b2  = (const float*)d_in[6];
  const float* W2r = (const float*)d_in[7];
  const float* W3l = (const float*)d_in[8];
  const float* b3  = (const float*)d_in[9];
  const float* W3r = (const float*)d_in[10];
  const int* src = ei;
  const int* dst = ei + N_EDGES;

  char* p = (char*)d_ws;
  auto alloc = [&](size_t bytes) { char* r = p; p += (bytes + 255) & ~(size_t)255; return r; };
  int*   deg     = (int*)alloc((size_t)N_NODES * 4);
  int*   off     = (int*)alloc((size_t)(N_NODES + 1) * 4);
  int*   cur     = (int*)alloc((size_t)N_NODES * 4);
  int*   csr     = (int*)alloc((size_t)N_EDGES * 4);
  float* inv_deg = (float*)alloc((size_t)N_NODES * 4);
  short* Wc1     = (short*)alloc((size_t)1024 * F_DIM * 2);
  short* Wc2     = (short*)alloc((size_t)1024 * H_DIM * 2);
  short* Cbuf    = (short*)alloc((size_t)MP * 1024 * 2);   // bf16 y|z
  short* hbuf    = (short*)alloc((size_t)MP * 512 * 2);
  float* y3z3    = (float*)alloc((size_t)N_NODES * 12 * 4);

  float* h_out   = (float*)d_out;                          // [N][512]
  float* o_out   = (float*)d_out + (size_t)N_NODES * 512;  // [N][6]

  // CSR build
  hipMemsetAsync(deg, 0, (size_t)N_NODES * 4, stream);
  count_deg<<<(N_EDGES + 255) / 256, 256, 0, stream>>>(dst, deg, N_EDGES);
  scan_deg<<<1, 1024, 0, stream>>>(deg, off, inv_deg, cur, N_NODES);
  fill_csr<<<(N_EDGES + 255) / 256, 256, 0, stream>>>(src, dst, off, cur, csr, N_EDGES);

  // weights -> bf16 (both layers, one launch)
  {
    long total = 2L * H_DIM * F_DIM + 2L * H_DIM * H_DIM;
    cvt_weights<<<(int)((total / 8 + 255) / 256), 256, 0, stream>>>(
        W1l, W1r, Wc1, W2l, W2r, Wc2);
  }

  // ---- layer 1 (A = x f32, converted LDS->reg inside the GEMM) ----
  gemm_bt_t<1><<<(MP / 128) * (1024 / 128), 256, 0, stream>>>(
      (const void*)x, Wc1, Cbuf, N_NODES, 1024, F_DIM);
  agg_combine<<<N_NODES, 128, 0, stream>>>(Cbuf, off, csr, inv_deg, b1, hbuf, nullptr);

  // ---- layer 2 (A = hbuf bf16) ----
  gemm_bt_t<0><<<(MP / 128) * (1024 / 128), 256, 0, stream>>>(
      (const void*)hbuf, Wc2, Cbuf, MP, 1024, H_DIM);
  agg_combine<<<N_NODES, 128, 0, stream>>>(Cbuf, off, csr, inv_deg, b2, nullptr, h_out);

  // ---- layer 3 ----
  l3_gemm<<<(N_NODES + 15) / 16, 256, 0, stream>>>(h_out, W3l, W3r, y3z3, N_NODES);
  final_out<<<(N_NODES * 6 + 255) / 256, 256, 0, stream>>>(y3z3, off, csr, inv_deg, b3, o_out, N_NODES);
}

// Round 13
// 249.310 us; speedup vs baseline: 1.1629x; 1.0472x over previous
//
#include <hip/hip_runtime.h>
#include <hip/hip_bf16.h>

// GraphSAGE 3-layer, MI355X. Aggregate AFTER projection (mean-agg commutes
// with matmul), so edge gathers happen in 512-dim, not 4096-dim.
// R13 (final form): R10 structure restored — the measured best across 12
// rounds (252.2us). GEMM = 128x128 tile, BK=32, double-buffered LDS,
// 4 blocks/CU, 0-conflict XOR layout, XCD swizzle. Both cvt-fusion
// directions (R6-9 produce-side, R12 consume-side) measured net-negative
// and are closed. Only delta vs R10: the two conversion kernels merged
// into one launch (cvt_all).

#define N_NODES 10000
#define N_EDGES 80000
#define F_DIM   4096
#define H_DIM   512
#define C_DIM   6
#define MP      10112   // 79 * 128, M padded for GEMM tiling

typedef __attribute__((ext_vector_type(4))) float f32x4;
typedef __attribute__((ext_vector_type(8))) short bf16x8;

__device__ __forceinline__ unsigned short f2bf(float f) {
  unsigned int u = __float_as_uint(f);
  u += 0x7FFFu + ((u >> 16) & 1u);   // round-to-nearest-even
  return (unsigned short)(u >> 16);
}

__device__ __forceinline__ f32x4 unpack_bf4(uint2 u) {
  f32x4 r;
  r[0] = __uint_as_float(u.x << 16);
  r[1] = __uint_as_float(u.x & 0xFFFF0000u);
  r[2] = __uint_as_float(u.y << 16);
  r[3] = __uint_as_float(u.y & 0xFFFF0000u);
  return r;
}

__device__ __forceinline__ void gload16(const short* g, short* l) {
  __builtin_amdgcn_global_load_lds(
      (const __attribute__((address_space(1))) unsigned int*)g,
      (__attribute__((address_space(3))) unsigned int*)l, 16, 0, 0);
}

// ---------------- CSR build ----------------
__global__ void count_deg(const int* __restrict__ dst, int* __restrict__ deg, int e) {
  int i = blockIdx.x * 256 + threadIdx.x;
  if (i < e) atomicAdd(&deg[dst[i]], 1);
}

// Single-block shuffle scan: 1024 threads x CH=10 contiguous elems = 10240 >= N.
// Also zeroes cur[] (used by fill_csr afterwards).
__global__ __launch_bounds__(1024) void scan_deg(const int* __restrict__ deg,
                                                 int* __restrict__ off,
                                                 float* __restrict__ inv_deg,
                                                 int* __restrict__ cur, int n) {
  __shared__ int wtot[16];
  const int CH = 10;
  int t = threadIdx.x;
  int lane = t & 63, wid = t >> 6;
  int base = t * CH;
  int v[CH];
  int s = 0;
#pragma unroll
  for (int j = 0; j < CH; ++j) {
    int i = base + j;
    v[j] = (i < n) ? deg[i] : 0;
    s += v[j];
  }
  int incl = s;
#pragma unroll
  for (int o = 1; o < 64; o <<= 1) {
    int u = __shfl_up(incl, o, 64);
    if (lane >= o) incl += u;
  }
  if (lane == 63) wtot[wid] = incl;
  __syncthreads();
  if (wid == 0 && lane < 16) {
    int w = wtot[lane];
    int wi = w;
#pragma unroll
    for (int o = 1; o < 16; o <<= 1) {
      int u = __shfl_up(wi, o, 64);
      if (lane >= o) wi += u;
    }
    wtot[lane] = wi - w;   // exclusive wave offset
  }
  __syncthreads();
  int run = wtot[wid] + incl - s;  // exclusive prefix for this thread's chunk
#pragma unroll
  for (int j = 0; j < CH; ++j) {
    int i = base + j;
    if (i < n) {
      run += v[j];
      off[i + 1] = run;
      inv_deg[i] = 1.0f / fmaxf((float)v[j], 1.0f);
      cur[i] = 0;
    }
  }
  if (t == 0) off[0] = 0;
}

__global__ void fill_csr(const int* __restrict__ src, const int* __restrict__ dst,
                         const int* __restrict__ off, int* __restrict__ cur,
                         int* __restrict__ csr, int e) {
  int i = blockIdx.x * 256 + threadIdx.x;
  if (i < e) {
    int d = dst[i];
    int p = atomicAdd(&cur[d], 1);
    csr[off[d] + p] = src[i];
  }
}

// ---------------- fused dtype conversion (one launch) ----------------
// Range 0: x [N_NODES*F_DIM] -> xb (pad to MP rows with zeros)
// Range 1: [W1l;W1r] -> Wc1 (2*512*4096)
// Range 2: [W2l;W2r] -> Wc2 (2*512*512)
__global__ void cvt_all(const float* __restrict__ x, short* __restrict__ xb,
                        const float* __restrict__ w1l, const float* __restrict__ w1r,
                        short* __restrict__ d1,
                        const float* __restrict__ w2l, const float* __restrict__ w2r,
                        short* __restrict__ d2) {
  const long nx  = (long)MP * F_DIM;          // padded x elems
  const long nxv = (long)N_NODES * F_DIM;     // valid x elems
  const long h1  = (long)H_DIM * F_DIM;
  const long h2  = (long)H_DIM * H_DIM;
  long idx = ((long)blockIdx.x * 256 + threadIdx.x) * 8;
  const float* s;
  short* d;
  if (idx < nx) {
    d = xb + idx;
    if (idx >= nxv) {   // padded tail: zero
      unsigned short z[8] = {0, 0, 0, 0, 0, 0, 0, 0};
      *(bf16x8*)d = *(bf16x8*)z;
      return;
    }
    s = x + idx;
  } else {
    long o1 = idx - nx;
    if (o1 < 2 * h1) {
      s = (o1 < h1) ? (w1l + o1) : (w1r + (o1 - h1));
      d = d1 + o1;
    } else {
      long o2 = o1 - 2 * h1;
      if (o2 >= 2 * h2) return;
      s = (o2 < h2) ? (w2l + o2) : (w2r + (o2 - h2));
      d = d2 + o2;
    }
  }
  f32x4 a = *(const f32x4*)s;
  f32x4 b = *(const f32x4*)(s + 4);
  unsigned short o[8];
  o[0] = f2bf(a[0]); o[1] = f2bf(a[1]); o[2] = f2bf(a[2]); o[3] = f2bf(a[3]);
  o[4] = f2bf(b[0]); o[5] = f2bf(b[1]); o[6] = f2bf(b[2]); o[7] = f2bf(b[3]);
  *(bf16x8*)d = *(bf16x8*)o;
}

// ---------------- bf16 MFMA GEMM: C[M][Nt] = A[M][K] @ B[Nt][K]^T, C bf16 ----
// 128x128 tile, 4 waves (2x2 of 64x64), 16x16x32 MFMA, BK=32.
// Double-buffered LDS (4 x 8KB = 32KB) -> 4 blocks/CU. XCD block swizzle.
// LDS layout: 2 rows per 128B line, slot s = u ^ (L&7), u = (row&1)*4 | kslot
// (measured 0 conflicts). gload_lds dest linear; global source
// inverse-permuted (both-sides rule).
__global__ __launch_bounds__(256, 4) void gemm_bt(
    const short* __restrict__ A, const short* __restrict__ B,
    short* __restrict__ C, int Nt, int K) {
  __shared__ short lds[4 * 4096];   // A0@0, B0@4096, A1@8192, B1@12288 (shorts)
  const int tiles_n = Nt >> 7;
  const int cpx = gridDim.x >> 3;                       // blocks per XCD
  const int swz = (blockIdx.x & 7) * cpx + (blockIdx.x >> 3);
  const int bm = swz / tiles_n;
  const int bn = swz % tiles_n;
  const int t = threadIdx.x;
  const int lane = t & 63;
  const int w = t >> 6;
  const int wr = w >> 1, wc = w & 1;
  const int lr = lane & 15, lk = lane >> 4;

  f32x4 acc[4][4] = {};

  // staging map: physical 16B chunk c = t + j*256 (c in [0,512), LDS offset
  // 16c, linear in lane as gload_lds requires). L = c>>3 (128B line),
  // s = c&7 (slot), u = s ^ (L&7) -> holds row 2L+(u>>2), col (u&3)*8 shorts.
  const short* pA[2];
  const short* pB[2];
  int dof[2];
#pragma unroll
  for (int j = 0; j < 2; ++j) {
    int c = t + j * 256;
    int L = c >> 3, s = c & 7;
    int u = s ^ (L & 7);
    int row = 2 * L + (u >> 2), col = (u & 3) * 8;
    pA[j] = A + (size_t)(bm * 128 + row) * K + col;
    pB[j] = B + (size_t)(bn * 128 + row) * K + col;
    dof[j] = c * 8;
  }

  const int NT = K >> 5;

  // prologue: stage tile 0 into buffer 0
#pragma unroll
  for (int j = 0; j < 2; ++j) gload16(pA[j], lds + dof[j]);
#pragma unroll
  for (int j = 0; j < 2; ++j) gload16(pB[j], lds + 4096 + dof[j]);
  __syncthreads();

  int cur = 0;
  for (int kt = 0; kt < NT; ++kt) {
    short* bufA = lds + cur * 8192;
    short* bufB = bufA + 4096;
    // phase 1: issue next-tile staging into the other buffer
    if (kt + 1 < NT) {
      int k0 = (kt + 1) << 5;
      short* nA = lds + (cur ^ 1) * 8192;
#pragma unroll
      for (int j = 0; j < 2; ++j) gload16(pA[j] + k0, nA + dof[j]);
#pragma unroll
      for (int j = 0; j < 2; ++j) gload16(pB[j] + k0, nA + 4096 + dof[j]);
    }
    // phase 2: ds_read fragments (swizzled) + MFMA
    bf16x8 a[4], b[4];
#pragma unroll
    for (int m = 0; m < 4; ++m) {
      int r = wr * 64 + m * 16 + lr;
      int byte = (r >> 1) * 128 + ((((r & 1) * 4 + lk) ^ ((r >> 1) & 7)) * 16);
      a[m] = *(bf16x8*)((char*)bufA + byte);
    }
#pragma unroll
    for (int n = 0; n < 4; ++n) {
      int r = wc * 64 + n * 16 + lr;
      int byte = (r >> 1) * 128 + ((((r & 1) * 4 + lk) ^ ((r >> 1) & 7)) * 16);
      b[n] = *(bf16x8*)((char*)bufB + byte);
    }
#pragma unroll
    for (int m = 0; m < 4; ++m)
#pragma unroll
      for (int n = 0; n < 4; ++n)
        acc[m][n] = __builtin_amdgcn_mfma_f32_16x16x32_bf16(a[m], b[n], acc[m][n], 0, 0, 0);
    __syncthreads();   // drains next-tile gload_lds + LDS fence
    cur ^= 1;
  }

  const int crow0 = bm * 128 + wr * 64 + lk * 4;   // C/D: col=lane&15, row=(lane>>4)*4+j
  const int ccol0 = bn * 128 + wc * 64 + lr;
#pragma unroll
  for (int m = 0; m < 4; ++m)
#pragma unroll
    for (int n = 0; n < 4; ++n)
#pragma unroll
      for (int j = 0; j < 4; ++j)
        C[(size_t)(crow0 + m * 16 + j) * Nt + ccol0 + n * 16] =
            (short)f2bf(acc[m][n][j]);
}

// ---------------- fused CSR mean-aggregate + combine (bf16 Y, f32 accum) ----
// out_i = relu( mean_j Y[j][0:512] + b + Y[i][512:1024] ), write bf16 and/or f32.
__global__ __launch_bounds__(128) void agg_combine(
    const short* __restrict__ Y, const int* __restrict__ off, const int* __restrict__ csr,
    const float* __restrict__ inv_deg, const float* __restrict__ bias,
    short* __restrict__ hb, float* __restrict__ hf) {
  int i = blockIdx.x;
  int t = threadIdx.x;             // 4 bf16 cols (8B) of the 512 agg cols
  int e0 = off[i], e1 = off[i + 1];
  f32x4 s = {0.f, 0.f, 0.f, 0.f};
  for (int e = e0; e < e1; ++e) {
    int sn = csr[e];
    uint2 u = ((const uint2*)(Y + (size_t)sn * 1024))[t];   // row stride 1024 bf16
    s += unpack_bf4(u);
  }
  float id = inv_deg[i];
  uint2 zu = ((const uint2*)(Y + (size_t)i * 1024 + 512))[t];  // cols 512..1023
  f32x4 z = unpack_bf4(zu);
  f32x4 b = ((const f32x4*)bias)[t];
  f32x4 r;
#pragma unroll
  for (int j = 0; j < 4; ++j) r[j] = fmaxf(s[j] * id + b[j] + z[j], 0.f);
  if (hf) ((f32x4*)hf)[(size_t)i * 128 + t] = r;
  if (hb) {
    unsigned short o[4] = {f2bf(r[0]), f2bf(r[1]), f2bf(r[2]), f2bf(r[3])};
    *(uint2*)&hb[(size_t)i * 512 + t * 4] = *(uint2*)o;
  }
}

// ---------------- layer 3: [N,512] f32 @ [12,512]^T -> y3z3 [N][12] ----------------
// 16 rows per block (625 blocks, weight LDS-load amortized 4x).
__global__ __launch_bounds__(256) void l3_gemm(const float* __restrict__ h2,
                                               const float* __restrict__ w3l,
                                               const float* __restrict__ w3r,
                                               float* __restrict__ y3z3, int n) {
  __shared__ float wsh[12 * 512];
  int t = threadIdx.x;
  for (int idx = t; idx < 12 * 512; idx += 256) {
    int r = idx >> 9, c = idx & 511;
    wsh[idx] = (r < 6) ? w3l[r * 512 + c] : w3r[(r - 6) * 512 + c];
  }
  __syncthreads();
  int wid = t >> 6, lane = t & 63;
#pragma unroll
  for (int rr = 0; rr < 4; ++rr) {
    int row = blockIdx.x * 16 + rr * 4 + wid;
    if (row >= n) continue;
    const f32x4* h4 = (const f32x4*)(h2 + (size_t)row * 512);
    f32x4 ha = h4[lane * 2], hb = h4[lane * 2 + 1];
#pragma unroll
    for (int c = 0; c < 12; ++c) {
      const f32x4* w4 = (const f32x4*)&wsh[c * 512];
      f32x4 wa = w4[lane * 2], wb = w4[lane * 2 + 1];
      float s = ha[0] * wa[0] + ha[1] * wa[1] + ha[2] * wa[2] + ha[3] * wa[3]
              + hb[0] * wb[0] + hb[1] * wb[1] + hb[2] * wb[2] + hb[3] * wb[3];
#pragma unroll
      for (int o = 32; o; o >>= 1) s += __shfl_down(s, o, 64);
      if (lane == 0) y3z3[(size_t)row * 12 + c] = s;
    }
  }
}

__global__ void final_out(const float* __restrict__ y3z3, const int* __restrict__ off,
                          const int* __restrict__ csr, const float* __restrict__ inv_deg,
                          const float* __restrict__ b3, float* __restrict__ out, int n) {
  int idx = blockIdx.x * 256 + threadIdx.x;
  if (idx >= n * 6) return;
  int i = idx / 6, c = idx - i * 6;
  float s = 0.f;
  int e0 = off[i], e1 = off[i + 1];
  for (int e = e0; e < e1; ++e) s += y3z3[(size_t)csr[e] * 12 + c];
  out[idx] = s * inv_deg[i] + b3[c] + y3z3[(size_t)i * 12 + 6 + c];
}

// ---------------- host ----------------
extern "C" void kernel_launch(void* const* d_in, const int* in_sizes, int n_in,
                              void* d_out, int out_size, void* d_ws, size_t ws_size,
                              hipStream_t stream) {
  const float* x   = (const float*)d_in[0];
  const int*   ei  = (const int*)d_in[1];
  const float* W1l = (const float*)d_in[2];
  const float* b1  = (const float*)d_in[3];
  const float* W1r = (const float*)d_in[4];
  const float* W2l = (const float*)d_in[5];
  const float* b2  = (const float*)d_in[6];
  const float* W2r = (const float*)d_in[7];
  const float* W3l = (const float*)d_in[8];
  const float* b3  = (const float*)d_in[9];
  const float* W3r = (const float*)d_in[10];
  const int* src = ei;
  const int* dst = ei + N_EDGES;

  char* p = (char*)d_ws;
  auto alloc = [&](size_t bytes) { char* r = p; p += (bytes + 255) & ~(size_t)255; return r; };
  int*   deg     = (int*)alloc((size_t)N_NODES * 4);
  int*   off     = (int*)alloc((size_t)(N_NODES + 1) * 4);
  int*   cur     = (int*)alloc((size_t)N_NODES * 4);
  int*   csr     = (int*)alloc((size_t)N_EDGES * 4);
  float* inv_deg = (float*)alloc((size_t)N_NODES * 4);
  short* xb      = (short*)alloc((size_t)MP * F_DIM * 2);
  short* Wc1     = (short*)alloc((size_t)1024 * F_DIM * 2);
  short* Wc2     = (short*)alloc((size_t)1024 * H_DIM * 2);
  short* Cbuf    = (short*)alloc((size_t)MP * 1024 * 2);   // bf16 y|z
  short* hbuf    = (short*)alloc((size_t)MP * 512 * 2);
  float* y3z3    = (float*)alloc((size_t)N_NODES * 12 * 4);

  float* h_out   = (float*)d_out;                          // [N][512]
  float* o_out   = (float*)d_out + (size_t)N_NODES * 512;  // [N][6]

  // CSR build
  hipMemsetAsync(deg, 0, (size_t)N_NODES * 4, stream);
  count_deg<<<(N_EDGES + 255) / 256, 256, 0, stream>>>(dst, deg, N_EDGES);
  scan_deg<<<1, 1024, 0, stream>>>(deg, off, inv_deg, cur, N_NODES);
  fill_csr<<<(N_EDGES + 255) / 256, 256, 0, stream>>>(src, dst, off, cur, csr, N_EDGES);

  // x + both weight sets -> bf16, single launch
  {
    long total = (long)MP * F_DIM + 2L * H_DIM * F_DIM + 2L * H_DIM * H_DIM;
    cvt_all<<<(int)((total / 8 + 255) / 256), 256, 0, stream>>>(
        x, xb, W1l, W1r, Wc1, W2l, W2r, Wc2);
  }

  // ---- layer 1 ----
  gemm_bt<<<(MP / 128) * (1024 / 128), 256, 0, stream>>>(xb, Wc1, Cbuf, 1024, F_DIM);
  agg_combine<<<N_NODES, 128, 0, stream>>>(Cbuf, off, csr, inv_deg, b1, hbuf, nullptr);

  // ---- layer 2 ----
  gemm_bt<<<(MP / 128) * (1024 / 128), 256, 0, stream>>>(hbuf, Wc2, Cbuf, 1024, H_DIM);
  agg_combine<<<N_NODES, 128, 0, stream>>>(Cbuf, off, csr, inv_deg, b2, nullptr, h_out);

  // ---- layer 3 ----
  l3_gemm<<<(N_NODES + 15) / 16, 256, 0, stream>>>(h_out, W3l, W3r, y3z3, N_NODES);
  final_out<<<(N_NODES * 6 + 255) / 256, 256, 0, stream>>>(y3z3, off, csr, inv_deg, b3, o_out, N_NODES);
}